// Round 3
// baseline (35.592 us; speedup 1.0000x reference)
//
#include <hip/hip_runtime.h>

#define SPECIAL_OFFSET 72      // 52 + NUM_BET_BINS(20)
#define NUM_SPECIAL 8
#define D_MODEL 256
#define NUM_CONTEXT 16
#define LN_EPS 1e-5f
#define TOK_PER_WAVE 16

typedef float vfloat4 __attribute__((ext_vector_type(4)));   // native vec for nt-store

// ---- rare-path helpers (wave-uniform calls; ~2.5% of tokens) ----

__device__ __noinline__ float4 mlp_cls_path(const float* __restrict__ xf,  // ctx_feat + tok*16
                                            const float* __restrict__ W,
                                            const float* __restrict__ b,
                                            const float* __restrict__ g,
                                            const float* __restrict__ be,
                                            int d0)
{
    const float x0 = xf[0], x1 = xf[1], x2 = xf[2];
    const float4 w0 = *reinterpret_cast<const float4*>(&W[0 * D_MODEL + d0]);
    const float4 w1 = *reinterpret_cast<const float4*>(&W[1 * D_MODEL + d0]);
    const float4 w2 = *reinterpret_cast<const float4*>(&W[2 * D_MODEL + d0]);
    const float4 bb = *reinterpret_cast<const float4*>(&b[d0]);
    float h0 = fmaf(x0, w0.x, fmaf(x1, w1.x, fmaf(x2, w2.x, bb.x)));
    float h1 = fmaf(x0, w0.y, fmaf(x1, w1.y, fmaf(x2, w2.y, bb.y)));
    float h2 = fmaf(x0, w0.z, fmaf(x1, w1.z, fmaf(x2, w2.z, bb.z)));
    float h3 = fmaf(x0, w0.w, fmaf(x1, w1.w, fmaf(x2, w2.w, bb.w)));

    float s  = h0 + h1 + h2 + h3;
    float ss = h0 * h0 + h1 * h1 + h2 * h2 + h3 * h3;
    #pragma unroll
    for (int m = 1; m < 64; m <<= 1) {
        s  += __shfl_xor(s,  m, 64);
        ss += __shfl_xor(ss, m, 64);
    }
    const float mu  = s * (1.f / 256.f);
    const float var = ss * (1.f / 256.f) - mu * mu;
    const float inv = rsqrtf(var + LN_EPS);
    const float4 gg = *reinterpret_cast<const float4*>(&g[d0]);
    const float4 bt = *reinterpret_cast<const float4*>(&be[d0]);
    float4 r;
    r.x = fmaxf((h0 - mu) * inv * gg.x + bt.x, 0.f);
    r.y = fmaxf((h1 - mu) * inv * gg.y + bt.y, 0.f);
    r.z = fmaxf((h2 - mu) * inv * gg.z + bt.z, 0.f);
    r.w = fmaxf((h3 - mu) * inv * gg.w + bt.w, 0.f);
    return r;
}

__device__ __noinline__ float4 mlp_ctx_path(const float* __restrict__ xf,  // ctx_feat + tok*16
                                            const float* __restrict__ W,
                                            const float* __restrict__ b,
                                            const float* __restrict__ g,
                                            const float* __restrict__ be,
                                            int d0)
{
    const float4 bb = *reinterpret_cast<const float4*>(&b[d0]);
    float h0 = bb.x, h1 = bb.y, h2 = bb.z, h3 = bb.w;
    #pragma unroll
    for (int k = 0; k < NUM_CONTEXT; ++k) {
        const float xk = xf[k];                                     // uniform broadcast
        const float4 w = *reinterpret_cast<const float4*>(&W[k * D_MODEL + d0]);
        h0 = fmaf(xk, w.x, h0);
        h1 = fmaf(xk, w.y, h1);
        h2 = fmaf(xk, w.z, h2);
        h3 = fmaf(xk, w.w, h3);
    }
    float s  = h0 + h1 + h2 + h3;
    float ss = h0 * h0 + h1 * h1 + h2 * h2 + h3 * h3;
    #pragma unroll
    for (int m = 1; m < 64; m <<= 1) {
        s  += __shfl_xor(s,  m, 64);
        ss += __shfl_xor(ss, m, 64);
    }
    const float mu  = s * (1.f / 256.f);
    const float var = ss * (1.f / 256.f) - mu * mu;
    const float inv = rsqrtf(var + LN_EPS);
    const float4 gg = *reinterpret_cast<const float4*>(&g[d0]);
    const float4 bt = *reinterpret_cast<const float4*>(&be[d0]);
    float4 r;
    r.x = fmaxf((h0 - mu) * inv * gg.x + bt.x, 0.f);
    r.y = fmaxf((h1 - mu) * inv * gg.y + bt.y, 0.f);
    r.z = fmaxf((h2 - mu) * inv * gg.z + bt.z, 0.f);
    r.w = fmaxf((h3 - mu) * inv * gg.w + bt.w, 0.f);
    return r;
}

// One wave owns 16 CONSECUTIVE tokens. All 16 ids come from ONE coalesced
// load (lane l reads id l&15), broadcast per-token via width-16 shfl.
// Fully-unrolled store loop -> 16 independent dwordx4 nt stores back-to-back.
__global__ __launch_bounds__(256, 8) void ContextEmbedding_35012573397647_kernel(
    const int*   __restrict__ token_ids,   // [N]
    const float* __restrict__ ctx_feat,    // [N, 16]
    const float* __restrict__ emb_table,   // [8, 256]
    const float* __restrict__ W_cls, const float* __restrict__ b_cls,
    const float* __restrict__ g_cls, const float* __restrict__ beta_cls,
    const float* __restrict__ W_ctx, const float* __restrict__ b_ctx,
    const float* __restrict__ g_ctx, const float* __restrict__ beta_ctx,
    float*       __restrict__ out,         // [N, 256]
    int n_tok)
{
    const int lane        = threadIdx.x & 63;
    const int wave_in_blk = threadIdx.x >> 6;                       // 0..3
    const int waves_total = (gridDim.x * blockDim.x) >> 6;
    const int d0          = lane << 2;
    const int n_batch     = (n_tok + TOK_PER_WAVE - 1) / TOK_PER_WAVE;

    for (int batch = blockIdx.x * 4 + wave_in_blk; batch < n_batch; batch += waves_total) {
        const int tok_base = batch * TOK_PER_WAVE;

        // one coalesced id load for the whole batch (4x replicated across the wave)
        const int idx = tok_base + (lane & 15);
        const int myid = (idx < n_tok) ? token_ids[idx] : -1;

        #pragma unroll
        for (int i = 0; i < TOK_PER_WAVE; ++i) {
            const int tok = tok_base + i;
            if (tok >= n_tok) break;
            const int tid = __shfl(myid, i, 16);                    // wave-uniform

            float4 o; o.x = 0.f; o.y = 0.f; o.z = 0.f; o.w = 0.f;
            if (tid >= SPECIAL_OFFSET && tid < SPECIAL_OFFSET + NUM_SPECIAL) {
                o = *reinterpret_cast<const float4*>(
                    &emb_table[(tid - SPECIAL_OFFSET) * D_MODEL + d0]);
                if (tid == SPECIAL_OFFSET + 0) {
                    const float4 m = mlp_cls_path(&ctx_feat[(size_t)tok * NUM_CONTEXT],
                                                  W_cls, b_cls, g_cls, beta_cls, d0);
                    o.x += m.x; o.y += m.y; o.z += m.z; o.w += m.w;
                } else if (tid == SPECIAL_OFFSET + 1) {
                    const float4 m = mlp_ctx_path(&ctx_feat[(size_t)tok * NUM_CONTEXT],
                                                  W_ctx, b_ctx, g_ctx, beta_ctx, d0);
                    o.x += m.x; o.y += m.y; o.z += m.z; o.w += m.w;
                }
            }
            vfloat4 ov; ov.x = o.x; ov.y = o.y; ov.z = o.z; ov.w = o.w;
            __builtin_nontemporal_store(ov, reinterpret_cast<vfloat4*>(
                &out[(size_t)tok * D_MODEL + d0]));
        }
    }
}

extern "C" void kernel_launch(void* const* d_in, const int* in_sizes, int n_in,
                              void* d_out, int out_size, void* d_ws, size_t ws_size,
                              hipStream_t stream) {
    const int*   token_ids = (const int*)  d_in[0];
    const float* ctx_feat  = (const float*)d_in[1];
    const float* emb_table = (const float*)d_in[2];
    const float* W_cls     = (const float*)d_in[3];
    const float* b_cls     = (const float*)d_in[4];
    const float* g_cls     = (const float*)d_in[5];
    const float* beta_cls  = (const float*)d_in[6];
    const float* W_ctx     = (const float*)d_in[7];
    const float* b_ctx     = (const float*)d_in[8];
    const float* g_ctx     = (const float*)d_in[9];
    const float* beta_ctx  = (const float*)d_in[10];
    float* out = (float*)d_out;

    const int n_tok   = in_sizes[0];                       // 131072
    const int n_batch = (n_tok + TOK_PER_WAVE - 1) / TOK_PER_WAVE;   // 8192
    int grid = (n_batch + 3) / 4;                          // 4 waves/block
    if (grid > 2048) grid = 2048;

    ContextEmbedding_35012573397647_kernel<<<grid, 256, 0, stream>>>(
        token_ids, ctx_feat, emb_table,
        W_cls, b_cls, g_cls, beta_cls,
        W_ctx, b_ctx, g_ctx, beta_ctx,
        out, n_tok);
}

// Round 4
// 27.104 us; speedup vs baseline: 1.3132x; 1.3132x over previous
//
#include <hip/hip_runtime.h>

#define SPECIAL_OFFSET 72      // 52 + NUM_BET_BINS(20)
#define NUM_SPECIAL 8
#define D_MODEL 256
#define NUM_CONTEXT 16
#define LN_EPS 1e-5f
#define TOK_PER_WAVE 16

// ---- rare-path helpers (wave-uniform calls; ~2.5% of tokens) ----

__device__ __noinline__ float4 mlp_cls_path(const float* __restrict__ xf,  // ctx_feat + tok*16
                                            const float* __restrict__ W,
                                            const float* __restrict__ b,
                                            const float* __restrict__ g,
                                            const float* __restrict__ be,
                                            int d0)
{
    const float x0 = xf[0], x1 = xf[1], x2 = xf[2];
    const float4 w0 = *reinterpret_cast<const float4*>(&W[0 * D_MODEL + d0]);
    const float4 w1 = *reinterpret_cast<const float4*>(&W[1 * D_MODEL + d0]);
    const float4 w2 = *reinterpret_cast<const float4*>(&W[2 * D_MODEL + d0]);
    const float4 bb = *reinterpret_cast<const float4*>(&b[d0]);
    float h0 = fmaf(x0, w0.x, fmaf(x1, w1.x, fmaf(x2, w2.x, bb.x)));
    float h1 = fmaf(x0, w0.y, fmaf(x1, w1.y, fmaf(x2, w2.y, bb.y)));
    float h2 = fmaf(x0, w0.z, fmaf(x1, w1.z, fmaf(x2, w2.z, bb.z)));
    float h3 = fmaf(x0, w0.w, fmaf(x1, w1.w, fmaf(x2, w2.w, bb.w)));

    float s  = h0 + h1 + h2 + h3;
    float ss = h0 * h0 + h1 * h1 + h2 * h2 + h3 * h3;
    #pragma unroll
    for (int m = 1; m < 64; m <<= 1) {
        s  += __shfl_xor(s,  m, 64);
        ss += __shfl_xor(ss, m, 64);
    }
    const float mu  = s * (1.f / 256.f);
    const float var = ss * (1.f / 256.f) - mu * mu;
    const float inv = rsqrtf(var + LN_EPS);
    const float4 gg = *reinterpret_cast<const float4*>(&g[d0]);
    const float4 bt = *reinterpret_cast<const float4*>(&be[d0]);
    float4 r;
    r.x = fmaxf((h0 - mu) * inv * gg.x + bt.x, 0.f);
    r.y = fmaxf((h1 - mu) * inv * gg.y + bt.y, 0.f);
    r.z = fmaxf((h2 - mu) * inv * gg.z + bt.z, 0.f);
    r.w = fmaxf((h3 - mu) * inv * gg.w + bt.w, 0.f);
    return r;
}

__device__ __noinline__ float4 mlp_ctx_path(const float* __restrict__ xf,  // ctx_feat + tok*16
                                            const float* __restrict__ W,
                                            const float* __restrict__ b,
                                            const float* __restrict__ g,
                                            const float* __restrict__ be,
                                            int d0)
{
    const float4 bb = *reinterpret_cast<const float4*>(&b[d0]);
    float h0 = bb.x, h1 = bb.y, h2 = bb.z, h3 = bb.w;
    #pragma unroll
    for (int k = 0; k < NUM_CONTEXT; ++k) {
        const float xk = xf[k];                                     // uniform broadcast
        const float4 w = *reinterpret_cast<const float4*>(&W[k * D_MODEL + d0]);
        h0 = fmaf(xk, w.x, h0);
        h1 = fmaf(xk, w.y, h1);
        h2 = fmaf(xk, w.z, h2);
        h3 = fmaf(xk, w.w, h3);
    }
    float s  = h0 + h1 + h2 + h3;
    float ss = h0 * h0 + h1 * h1 + h2 * h2 + h3 * h3;
    #pragma unroll
    for (int m = 1; m < 64; m <<= 1) {
        s  += __shfl_xor(s,  m, 64);
        ss += __shfl_xor(ss, m, 64);
    }
    const float mu  = s * (1.f / 256.f);
    const float var = ss * (1.f / 256.f) - mu * mu;
    const float inv = rsqrtf(var + LN_EPS);
    const float4 gg = *reinterpret_cast<const float4*>(&g[d0]);
    const float4 bt = *reinterpret_cast<const float4*>(&be[d0]);
    float4 r;
    r.x = fmaxf((h0 - mu) * inv * gg.x + bt.x, 0.f);
    r.y = fmaxf((h1 - mu) * inv * gg.y + bt.y, 0.f);
    r.z = fmaxf((h2 - mu) * inv * gg.z + bt.z, 0.f);
    r.w = fmaxf((h3 - mu) * inv * gg.w + bt.w, 0.f);
    return r;
}

// One wave owns 16 CONSECUTIVE tokens. All 16 ids come from ONE coalesced
// load (lane l reads id l&15), broadcast per-token via width-16 shfl.
// Fully-unrolled, branch-free store loop -> 16 dwordx4 stores back-to-back.
// NO nontemporal stores, NO tight VGPR cap (round-3 post-mortem: lb(256,8)
// forced VGPR=32 -> scratch spill -> +11.5MB writes and a regression).
__global__ __launch_bounds__(256, 2) void ContextEmbedding_35012573397647_kernel(
    const int*   __restrict__ token_ids,   // [N]
    const float* __restrict__ ctx_feat,    // [N, 16]
    const float* __restrict__ emb_table,   // [8, 256]
    const float* __restrict__ W_cls, const float* __restrict__ b_cls,
    const float* __restrict__ g_cls, const float* __restrict__ beta_cls,
    const float* __restrict__ W_ctx, const float* __restrict__ b_ctx,
    const float* __restrict__ g_ctx, const float* __restrict__ beta_ctx,
    float*       __restrict__ out,         // [N, 256]
    int n_tok)
{
    const int lane        = threadIdx.x & 63;
    const int wave_in_blk = threadIdx.x >> 6;                       // 0..3
    const int waves_total = (gridDim.x * blockDim.x) >> 6;
    const int d0          = lane << 2;
    const int n_batch     = n_tok / TOK_PER_WAVE;                   // full batches

    for (int batch = blockIdx.x * 4 + wave_in_blk; batch < n_batch; batch += waves_total) {
        const int tok_base = batch * TOK_PER_WAVE;

        // one coalesced id load for the whole batch (4x replicated across the wave)
        const int myid = token_ids[tok_base + (lane & 15)];

        #pragma unroll
        for (int i = 0; i < TOK_PER_WAVE; ++i) {
            const int tok = tok_base + i;
            const int tid = __shfl(myid, i, 16);                    // wave-uniform

            float4 o; o.x = 0.f; o.y = 0.f; o.z = 0.f; o.w = 0.f;
            if (tid >= SPECIAL_OFFSET && tid < SPECIAL_OFFSET + NUM_SPECIAL) {
                o = *reinterpret_cast<const float4*>(
                    &emb_table[(tid - SPECIAL_OFFSET) * D_MODEL + d0]);
                if (tid == SPECIAL_OFFSET + 0) {
                    const float4 m = mlp_cls_path(&ctx_feat[(size_t)tok * NUM_CONTEXT],
                                                  W_cls, b_cls, g_cls, beta_cls, d0);
                    o.x += m.x; o.y += m.y; o.z += m.z; o.w += m.w;
                } else if (tid == SPECIAL_OFFSET + 1) {
                    const float4 m = mlp_ctx_path(&ctx_feat[(size_t)tok * NUM_CONTEXT],
                                                  W_ctx, b_ctx, g_ctx, beta_ctx, d0);
                    o.x += m.x; o.y += m.y; o.z += m.z; o.w += m.w;
                }
            }
            *reinterpret_cast<float4*>(&out[(size_t)tok * D_MODEL + d0]) = o;
        }
    }

    // tail tokens (n_tok % 16 != 0) — never taken for the benched shape
    const int tail_start = n_batch * TOK_PER_WAVE;
    for (int tok = tail_start + blockIdx.x * 4 + wave_in_blk; tok < n_tok;
         tok += waves_total) {
        const int tid = token_ids[tok];
        float4 o; o.x = 0.f; o.y = 0.f; o.z = 0.f; o.w = 0.f;
        if (tid >= SPECIAL_OFFSET && tid < SPECIAL_OFFSET + NUM_SPECIAL) {
            o = *reinterpret_cast<const float4*>(
                &emb_table[(tid - SPECIAL_OFFSET) * D_MODEL + d0]);
            if (tid == SPECIAL_OFFSET + 0) {
                const float4 m = mlp_cls_path(&ctx_feat[(size_t)tok * NUM_CONTEXT],
                                              W_cls, b_cls, g_cls, beta_cls, d0);
                o.x += m.x; o.y += m.y; o.z += m.z; o.w += m.w;
            } else if (tid == SPECIAL_OFFSET + 1) {
                const float4 m = mlp_ctx_path(&ctx_feat[(size_t)tok * NUM_CONTEXT],
                                              W_ctx, b_ctx, g_ctx, beta_ctx, d0);
                o.x += m.x; o.y += m.y; o.z += m.z; o.w += m.w;
            }
        }
        *reinterpret_cast<float4*>(&out[(size_t)tok * D_MODEL + d0]) = o;
    }
}

extern "C" void kernel_launch(void* const* d_in, const int* in_sizes, int n_in,
                              void* d_out, int out_size, void* d_ws, size_t ws_size,
                              hipStream_t stream) {
    const int*   token_ids = (const int*)  d_in[0];
    const float* ctx_feat  = (const float*)d_in[1];
    const float* emb_table = (const float*)d_in[2];
    const float* W_cls     = (const float*)d_in[3];
    const float* b_cls     = (const float*)d_in[4];
    const float* g_cls     = (const float*)d_in[5];
    const float* beta_cls  = (const float*)d_in[6];
    const float* W_ctx     = (const float*)d_in[7];
    const float* b_ctx     = (const float*)d_in[8];
    const float* g_ctx     = (const float*)d_in[9];
    const float* beta_ctx  = (const float*)d_in[10];
    float* out = (float*)d_out;

    const int n_tok   = in_sizes[0];                       // 131072
    const int n_batch = n_tok / TOK_PER_WAVE;              // 8192
    int grid = (n_batch + 3) / 4;                          // 4 waves/block -> 2048
    if (grid > 2048) grid = 2048;
    if (grid < 1) grid = 1;

    ContextEmbedding_35012573397647_kernel<<<grid, 256, 0, stream>>>(
        token_ids, ctx_feat, emb_table,
        W_cls, b_cls, g_cls, beta_cls,
        W_ctx, b_ctx, g_ctx, beta_ctx,
        out, n_tok);
}